// Round 8
// baseline (196.215 us; speedup 1.0000x reference)
//
#include <hip/hip_runtime.h>
#include <hip/hip_bf16.h>
#include <math.h>

#define D 768
#define HEADS 16
#define DH 48
#define P2 256
#define KSEL 8

#define VSTRIDE 49   // (fallback kernel) pad 48 -> 49
#define PSTRIDE 33   // (fallback kernel) pad 32 -> 33

#define CONV_BLOCKS 1152   // 3 which * 8 b * 8 ystrip(TY=4) * 3 chunk * 2 xc
#define TOPK_BLOCKS 4096   // 32768 rows / (4 waves * 2 rows)

// ---------------------------------------------------------------------------
// Round 8: ABLATION SPLIT. prep_kernel carried three distinct workloads
// (conv, topk) in one dispatch name, and attn has never surfaced in the
// top-5 -- after 7 rounds the per-phase split is still unmeasured. Split
// into three dispatches so rocprof reports each:
//   topk_kernel: r0 top-8 scan, 2 rows/wave. No LDS now (r4's split
//     allocated 25.6KB to topk blocks that never used it, capping their
//     occupancy at 6 blocks/CU).
//   conv_kernel: r4 conv verbatim (best measured: 55.5us mixed) --
//     weights in LDS [tap][channel], window in regs, 64-bit addressing
//     (r7 proved the remat-driven MLP of this form beats strength-
//     reduced serial offsets: identical VALU-busy, less stall).
//   attn_kernel: unchanged.
// Order topk -> conv -> attn (conv output L2-hot for attn).
// ---------------------------------------------------------------------------

__global__ __launch_bounds__(256) void topk_kernel(
    const float* __restrict__ adjg,   // (32768,256)
    int* __restrict__ idxout)         // (32768,8)
{
    int wave = threadIdx.x >> 6;
    int lane = threadIdx.x & 63;
    int row0 = (blockIdx.x * 4 + wave) * 2;  // 0..32766

    const float* ar0 = adjg + (size_t)row0 * P2;
    const float* ar1 = ar0 + P2;
    float4 a0 = *(const float4*)(ar0 + lane * 4);
    float4 a1 = *(const float4*)(ar1 + lane * 4);
    float v0[4] = {a0.x, a0.y, a0.z, a0.w};
    float v1[4] = {a1.x, a1.y, a1.z, a1.w};

    int myidx0 = 0, myidx1 = 0;
    #pragma unroll
    for (int it = 0; it < KSEL; it++) {
        // local argmax for both rows (strict > keeps lowest slot on ties)
        float b0 = v0[0]; int s0 = 0;
        float b1 = v1[0]; int s1 = 0;
        if (v0[1] > b0) { b0 = v0[1]; s0 = 1; }
        if (v1[1] > b1) { b1 = v1[1]; s1 = 1; }
        if (v0[2] > b0) { b0 = v0[2]; s0 = 2; }
        if (v1[2] > b1) { b1 = v1[2]; s1 = 2; }
        if (v0[3] > b0) { b0 = v0[3]; s0 = 3; }
        if (v1[3] > b1) { b1 = v1[3]; s1 = 3; }
        // interleaved value-only max reductions (independent chains)
        float g0 = b0, g1 = b1;
        #pragma unroll
        for (int m = 32; m >= 1; m >>= 1) {
            g0 = fmaxf(g0, __shfl_xor(g0, m, 64));
            g1 = fmaxf(g1, __shfl_xor(g1, m, 64));
        }
        unsigned long long m0 = __ballot(b0 == g0);
        unsigned long long m1 = __ballot(b1 == g1);
        int wl0 = (int)__builtin_ctzll(m0);
        int wl1 = (int)__builtin_ctzll(m1);
        int ws0 = __shfl(s0, wl0, 64);
        int ws1 = __shfl(s1, wl1, 64);
        if (lane == it) { myidx0 = wl0 * 4 + ws0; myidx1 = wl1 * 4 + ws1; }
        if (lane == wl0) v0[ws0] = -INFINITY;
        if (lane == wl1) v1[ws1] = -INFINITY;
    }
    if (lane < KSEL) {
        idxout[(size_t)row0 * KSEL + lane]       = myidx0;
        idxout[(size_t)(row0 + 1) * KSEL + lane] = myidx1;
    }
}

__global__ __launch_bounds__(256) void conv_kernel(
    const float* __restrict__ x,      // (8,1024,768) fp32
    const float* __restrict__ w,      // (3,768,1,5,5)
    const float* __restrict__ gamma,  // (3,768)
    const float* __restrict__ beta,
    const float* __restrict__ mean,
    const float* __restrict__ var,
    float* __restrict__ qw, float* __restrict__ kw, float* __restrict__ vw)
{
    __shared__ float wLds[25][256];

    int bi    = blockIdx.x;              // 0..1151
    int which = bi / 384;                // 0=q 1=k 2=v
    int rem   = bi % 384;
    int b     = rem / 48;
    int rem2  = rem % 48;
    int ys    = rem2 / 6;                // 0..7
    int sub   = rem2 % 6;
    int chunk = sub >> 1;
    int xc    = sub & 1;
    int x0    = xc * 16;
    int y0    = ys * 4;                  // 0,4,...,28 (never crosses 16-bdy)
    int c     = chunk * 256 + threadIdx.x;

    int g = which * D + c;
    float inv = gamma[g] * rsqrtf(var[g] + 1e-5f);
    float sh  = beta[g] - mean[g] * inv;
    if (which == 0) {
        const float scale = 0.03608439182435161f;   // 768^-0.5 folded into q
        inv *= scale; sh *= scale;
    }

    // stage BN-folded weights in LDS: [tap][channel] -> lane-stride-1 reads
    {
        const float* wp = w + ((size_t)which * D + c) * 25;
        #pragma unroll
        for (int i = 0; i < 25; i++) wLds[i][threadIdx.x] = wp[i] * inv;
    }
    __syncthreads();

    float* dst = (which == 0) ? qw : (which == 1) ? kw : vw;

    const float* xb = x + (size_t)b * 1024 * D + c;

    // 8-row sliding window (rows y0-2 .. y0+5), 5 columns wide
    float a[8][5];
    bool yok[8];                         // wave-uniform predicates
    #pragma unroll
    for (int i = 0; i < 8; i++) {
        int yy = y0 - 2 + i;
        yok[i] = (yy >= 0 && yy < 32);
        #pragma unroll
        for (int j = 0; j < 5; j++) {
            int xxc = x0 - 2 + j;
            a[i][j] = (yok[i] && xxc >= 0 && xxc < 32)
                      ? xb[(yy * 32 + xxc) * D] : 0.f;
        }
    }

    int head = c / DH, cc = c % DH;
    int n = b * HEADS + head;
    int A = y0 >> 4;                     // same for all 4 rows of the strip

    #pragma unroll                       // FULL unroll: shifts become renames
    for (int t = 0; t < 16; t++) {
        int xx = x0 + t;
        float s[4] = {0.f, 0.f, 0.f, 0.f};
        #pragma unroll
        for (int i = 0; i < 5; i++)
        #pragma unroll
        for (int j = 0; j < 5; j++) {
            float wv = wLds[i * 5 + j][threadIdx.x];
            s[0] = fmaf(a[0 + i][j], wv, s[0]);
            s[1] = fmaf(a[1 + i][j], wv, s[1]);
            s[2] = fmaf(a[2 + i][j], wv, s[2]);
            s[3] = fmaf(a[3 + i][j], wv, s[3]);
        }
        int j0 = xx & 15, Bq = xx >> 4;
        int slot = A * 2 + Bq;
        #pragma unroll
        for (int r = 0; r < 4; r++) {
            int yq = y0 + r;
            int i0 = yq & 15;
            int win = i0 * 16 + j0;
            size_t off = (((size_t)n * P2 + win) * 4 + slot) * DH + cc;
            dst[off] = s[r] + sh;
        }
        if (t < 15) {                    // no dead refill on the last step
            #pragma unroll
            for (int i = 0; i < 8; i++)
            #pragma unroll
            for (int j = 0; j < 4; j++)
                a[i][j] = a[i][j + 1];
            int xn = xx + 3;
            bool xok = (xn < 32);
            #pragma unroll
            for (int i = 0; i < 8; i++) {
                int yy = y0 - 2 + i;
                a[i][4] = (yok[i] && xok) ? xb[(yy * 32 + xn) * D] : 0.f;
            }
        }
    }
}

// ---------------------------------------------------------------------------
// Kernel 2: attention, all-64-lane balanced (unchanged).
// ---------------------------------------------------------------------------
__global__ __launch_bounds__(256) void attn_kernel(
    const int*   __restrict__ idxin,  // (32768, 8)
    const float* __restrict__ qw,     // pre-scaled
    const float* __restrict__ kw,
    const float* __restrict__ vw,
    float* __restrict__ out)          // (8,1024,768) fp32
{
    __shared__ float4 vL[4][32 * 13];
    __shared__ float4 qL[4][4 * 13];
    __shared__ float  pL[4][4 * 36];

    int wave = threadIdx.x >> 6;
    int lane = threadIdx.x & 63;
    int B    = blockIdx.x;                 // 8192 blocks
    int n    = (B & 7) * 16 + (B >> 9);    // 0..127 (XCD swizzle)
    int wing = (B >> 3) & 63;
    int win  = wing * 4 + wave;            // 0..255
    int row  = n * P2 + win;
    int b    = n >> 4, head = n & 15;

    float4* vs4 = vL[wave];
    float4* qs4 = qL[wave];
    float*  ps  = pL[wave];

    int l2 = lane & 31, half = lane >> 5;
    int kk = l2 >> 2, tt = l2 & 3;
    int mywin = idxin[row * KSEL + kk];

    const float4* qp = (const float4*)(qw + ((size_t)n * P2 + win) * 192);
    if (lane < 48) {
        int r = lane / 12, c4 = lane % 12;
        qs4[r * 13 + c4] = qp[lane];
    }

    size_t gbase = (((size_t)n * P2 + mywin) * 4 + tt) * DH + half * 24;
    const float4* srcK = (const float4*)(kw + gbase);
    const float4* srcV = (const float4*)(vw + gbase);
    float4 kregh[6];
    #pragma unroll
    for (int j = 0; j < 6; j++) kregh[j] = srcK[j];
    #pragma unroll
    for (int j = 0; j < 6; j++) vs4[l2 * 13 + half * 6 + j] = srcV[j];
    __syncthreads();

    float s4[4];
    #pragma unroll
    for (int r = 0; r < 4; r++) {
        float acc = 0.f;
        #pragma unroll
        for (int j = 0; j < 6; j++) {
            float4 q4 = qs4[r * 13 + half * 6 + j];
            acc = fmaf(q4.x, kregh[j].x, acc);
            acc = fmaf(q4.y, kregh[j].y, acc);
            acc = fmaf(q4.z, kregh[j].z, acc);
            acc = fmaf(q4.w, kregh[j].w, acc);
        }
        s4[r] = acc;
    }
    #pragma unroll
    for (int r = 0; r < 4; r++)
        s4[r] += __shfl_xor(s4[r], 32, 64);

    #pragma unroll
    for (int e = 0; e < 2; e++) {
        int r = 2 * half + e;
        float sv = s4[r];
        float m = sv;
        #pragma unroll
        for (int mm = 16; mm >= 1; mm >>= 1)
            m = fmaxf(m, __shfl_xor(m, mm, 64));
        float p = __expf(sv - m);
        float sum = p;
        #pragma unroll
        for (int mm = 16; mm >= 1; mm >>= 1)
            sum += __shfl_xor(sum, mm, 64);
        ps[r * 36 + l2] = p / sum;
    }
    __syncthreads();

    if (lane < 48) {
        int r = lane / 12, c4 = lane % 12;
        const float4* psv = (const float4*)(ps + r * 36);
        float4 acc = {0.f, 0.f, 0.f, 0.f};
        #pragma unroll
        for (int k2q = 0; k2q < 8; k2q++) {
            float4 p4 = psv[k2q];
            float4 v0 = vs4[(k2q * 4 + 0) * 13 + c4];
            float4 v1 = vs4[(k2q * 4 + 1) * 13 + c4];
            float4 v2 = vs4[(k2q * 4 + 2) * 13 + c4];
            float4 v3 = vs4[(k2q * 4 + 3) * 13 + c4];
            acc.x = fmaf(p4.x, v0.x, acc.x); acc.y = fmaf(p4.x, v0.y, acc.y);
            acc.z = fmaf(p4.x, v0.z, acc.z); acc.w = fmaf(p4.x, v0.w, acc.w);
            acc.x = fmaf(p4.y, v1.x, acc.x); acc.y = fmaf(p4.y, v1.y, acc.y);
            acc.z = fmaf(p4.y, v1.z, acc.z); acc.w = fmaf(p4.y, v1.w, acc.w);
            acc.x = fmaf(p4.z, v2.x, acc.x); acc.y = fmaf(p4.z, v2.y, acc.y);
            acc.z = fmaf(p4.z, v2.z, acc.z); acc.w = fmaf(p4.z, v2.w, acc.w);
            acc.x = fmaf(p4.w, v3.x, acc.x); acc.y = fmaf(p4.w, v3.y, acc.y);
            acc.z = fmaf(p4.w, v3.z, acc.z); acc.w = fmaf(p4.w, v3.w, acc.w);
        }
        int i0 = win >> 4, j0 = win & 15;
        int Aq = r >> 1, Bq = r & 1;
        int rowp = Bq * 16 + i0, colp = Aq * 16 + j0;
        float* op = out + ((size_t)b * 1024 + rowp * 32 + colp) * D
                        + head * DH + c4 * 4;
        *(float4*)op = acc;
    }
}

// ---------------------------------------------------------------------------
// Fallback (zero workspace): fully fused, round-3 version.
// ---------------------------------------------------------------------------
__global__ __launch_bounds__(256) void fused_attn(
    const float* __restrict__ x,
    const float* __restrict__ adjg,
    const float* __restrict__ w,
    const float* __restrict__ gamma,
    const float* __restrict__ beta,
    const float* __restrict__ mean,
    const float* __restrict__ var,
    float* __restrict__ out)
{
    __shared__ float wL[3][25][48];
    __shared__ float bnI[3][48], bnS[3][48];
    __shared__ float qL[4][192];
    __shared__ float vL[4][32 * VSTRIDE];
    __shared__ float pL[4][4 * PSTRIDE];

    int tid  = threadIdx.x;
    int wave = tid >> 6, lane = tid & 63;
    int unit = blockIdx.x * 4 + wave;
    int n    = unit >> 8;
    int win  = unit & 255;
    int b    = n >> 4, head = n & 15;

    for (int j = tid; j < 3600; j += 256) {
        int chunk = j / 1200, rem = j % 1200, t = rem / 48, cc = rem % 48;
        wL[chunk][t][cc] = w[(size_t)chunk * D * 25 + (head * DH + cc) * 25 + t];
    }
    for (int j = tid; j < 144; j += 256) {
        int chunk = j / 48, cc = j % 48;
        int g = chunk * D + head * DH + cc;
        float inv = gamma[g] * rsqrtf(var[g] + 1e-5f);
        bnI[chunk][cc] = inv;
        bnS[chunk][cc] = beta[g] - mean[g] * inv;
    }
    __syncthreads();

    float* qs = qL[wave];
    float* vs = vL[wave];
    float* ps = pL[wave];

    const float* arow = adjg + ((size_t)n * P2 + win) * P2;
    float4 av4 = *(const float4*)(arow + lane * 4);
    float vals[4] = {av4.x, av4.y, av4.z, av4.w};

    int l2 = lane & 31;
    int kk = l2 >> 2, tt = l2 & 3;
    int mywin = 0;
    #pragma unroll
    for (int it = 0; it < KSEL; it++) {
        float bv = vals[0]; int bidx = lane * 4;
        #pragma unroll
        for (int s = 1; s < 4; s++)
            if (vals[s] > bv) { bv = vals[s]; bidx = lane * 4 + s; }
        #pragma unroll
        for (int m = 32; m >= 1; m >>= 1) {
            float ov = __shfl_xor(bv, m, 64);
            int   oi = __shfl_xor(bidx, m, 64);
            if (ov > bv || (ov == bv && oi < bidx)) { bv = ov; bidx = oi; }
        }
        if (kk == it) mywin = bidx;
        #pragma unroll
        for (int s = 0; s < 4; s++)
            if (lane * 4 + s == bidx) vals[s] = -INFINITY;
    }

    const float scale = 0.03608439182435161f;
    int i0 = win >> 4, j0 = win & 15;
    const float* xbh = x + (size_t)b * 1024 * D + head * DH;

    #pragma unroll
    for (int e = 0; e < 3; e++) {
        int idx = lane + 64 * e;
        int r = idx / 48, cc = idx % 48;
        int yq  = (r >> 1) * 16 + i0;
        int xq0 = (r & 1) * 16 + j0;
        float acc = 0.f;
        for (int ty = 0; ty < 5; ty++) {
            int yy = yq + ty - 2;
            if (yy < 0 || yy > 31) continue;
            for (int tx = 0; tx < 5; tx++) {
                int xx = xq0 + tx - 2;
                if (xx < 0 || xx > 31) continue;
                acc = fmaf(xbh[(size_t)(yy * 32 + xx) * D + cc],
                           wL[0][ty * 5 + tx][cc], acc);
            }
        }
        qs[idx] = (acc * bnI[0][cc] + bnS[0][cc]) * scale;
    }

    int half  = lane >> 5;
    int chunk = 1 + half;
    float accv[48];
    {
        int yk  = (tt >> 1) * 16 + (mywin >> 4);
        int xk0 = (tt & 1) * 16 + (mywin & 15);
        #pragma unroll
        for (int cc = 0; cc < 48; cc++) accv[cc] = 0.f;
        for (int ty = 0; ty < 5; ty++) {
            int yy = yk + ty - 2;
            if (yy < 0 || yy > 31) continue;
            for (int tx = 0; tx < 5; tx++) {
                int xx = xk0 + tx - 2;
                if (xx < 0 || xx > 31) continue;
                const float* px = xbh + (size_t)(yy * 32 + xx) * D;
                const float* wt = wL[chunk][ty * 5 + tx];
                #pragma unroll
                for (int c4 = 0; c4 < 12; c4++) {
                    float4 xv = *(const float4*)(px + c4 * 4);
                    accv[c4*4+0] = fmaf(xv.x, wt[c4*4+0], accv[c4*4+0]);
                    accv[c4*4+1] = fmaf(xv.y, wt[c4*4+1], accv[c4*4+1]);
                    accv[c4*4+2] = fmaf(xv.z, wt[c4*4+2], accv[c4*4+2]);
                    accv[c4*4+3] = fmaf(xv.w, wt[c4*4+3], accv[c4*4+3]);
                }
            }
        }
        #pragma unroll
        for (int cc = 0; cc < 48; cc++) {
            float val = accv[cc] * bnI[chunk][cc] + bnS[chunk][cc];
            if (half) vs[l2 * VSTRIDE + cc] = val;
            else      accv[cc] = val;
        }
    }
    __syncthreads();

    if (!half) {
        float s4[4] = {0.f, 0.f, 0.f, 0.f};
        #pragma unroll
        for (int c = 0; c < 48; c++) {
            float kc = accv[c];
            s4[0] = fmaf(qs[c],       kc, s4[0]);
            s4[1] = fmaf(qs[48 + c],  kc, s4[1]);
            s4[2] = fmaf(qs[96 + c],  kc, s4[2]);
            s4[3] = fmaf(qs[144 + c], kc, s4[3]);
        }
        #pragma unroll
        for (int r = 0; r < 4; r++) {
            float m = s4[r];
            #pragma unroll
            for (int mm = 16; mm >= 1; mm >>= 1)
                m = fmaxf(m, __shfl_xor(m, mm, 64));
            float p = __expf(s4[r] - m);
            float sum = p;
            #pragma unroll
            for (int mm = 16; mm >= 1; mm >>= 1)
                sum += __shfl_xor(sum, mm, 64);
            ps[r * PSTRIDE + l2] = p / sum;
        }
    }
    __syncthreads();

    #pragma unroll
    for (int e = 0; e < 3; e++) {
        int idx = lane + 64 * e;
        int r = idx / 48, c = idx % 48;
        float acc = 0.f;
        #pragma unroll
        for (int k2 = 0; k2 < 32; k2++)
            acc = fmaf(ps[r * PSTRIDE + k2], vs[k2 * VSTRIDE + c], acc);
        int Aq = r >> 1, Bq = r & 1;
        int rowp = Bq * 16 + i0, colp = Aq * 16 + j0;
        out[((size_t)b * 1024 + rowp * 32 + colp) * D + head * DH + c] = acc;
    }
}

extern "C" void kernel_launch(void* const* d_in, const int* in_sizes, int n_in,
                              void* d_out, int out_size, void* d_ws, size_t ws_size,
                              hipStream_t stream)
{
    const float* x     = (const float*)d_in[0];
    // d_in[1] = noise (unused by reference)
    const float* adjg  = (const float*)d_in[2];
    const float* w     = (const float*)d_in[3];
    const float* gamma = (const float*)d_in[4];
    const float* beta  = (const float*)d_in[5];
    const float* mean  = (const float*)d_in[6];
    const float* var   = (const float*)d_in[7];
    // d_in[8] = sparsity (=8, compile-time KSEL)

    const size_t NQKV   = (size_t)8 * HEADS * P2 * 4 * DH;   // 6291456 elements
    const size_t NROWS  = (size_t)8 * HEADS * P2;            // 32768
    const size_t need3  = 3 * NQKV * sizeof(float) + NROWS * KSEL * sizeof(int);

    if (ws_size >= need3) {
        float* qw  = (float*)d_ws;
        float* kw  = qw + NQKV;
        float* vw  = kw + NQKV;
        int*   idx = (int*)(vw + NQKV);
        topk_kernel<<<TOPK_BLOCKS, 256, 0, stream>>>(adjg, idx);
        conv_kernel<<<CONV_BLOCKS, 256, 0, stream>>>(
            x, w, gamma, beta, mean, var, qw, kw, vw);
        attn_kernel<<<8192, 256, 0, stream>>>(idx, qw, kw, vw, (float*)d_out);
    } else {
        fused_attn<<<8192, 256, 0, stream>>>(x, adjg, w, gamma, beta, mean, var,
                                             (float*)d_out);
    }
}

// Round 9
// 181.368 us; speedup vs baseline: 1.0819x; 1.0819x over previous
//
#include <hip/hip_runtime.h>
#include <hip/hip_bf16.h>
#include <math.h>

#define D 768
#define HEADS 16
#define DH 48
#define P2 256
#define KSEL 8

#define VSTRIDE 49   // (fallback kernel) pad 48 -> 49
#define PSTRIDE 33   // (fallback kernel) pad 32 -> 33

#define CONV_BLOCKS 1152   // 3 which * 8 b * 8 ystrip(TY=4) * 3 chunk * 2 xc
#define TOPK_BLOCKS 4096   // 32768 rows / (4 waves * 2 rows)

// Wave-local LDS fence: all attn LDS is wave-private (vL[wave] slices), so a
// block-wide __syncthreads is semantically unnecessary. DS ops within a wave
// complete in issue order; lgkmcnt(0) + "memory" clobber gives the
// write->read handoff without coupling the 4 waves' gather latencies.
#define WAVE_FENCE() asm volatile("s_waitcnt lgkmcnt(0)" ::: "memory")

// ---------------------------------------------------------------------------
// Kernel 1 (fused prep) — r4 verbatim (best measured: 55.5us):
//  blocks [0, 1152): depthwise 5x5 conv + BN, weights in LDS [tap][chan],
//    sliding window in regs, TY=4.
//  blocks [1152, 5248): top-8 scan, 2 rows per wave.
//  (r8 ablation split measured topk+conv serial ~12us slower than this
//   mixed dispatch -> merged back.)
// ---------------------------------------------------------------------------
__global__ __launch_bounds__(256) void prep_kernel(
    const float* __restrict__ x,      // (8,1024,768) fp32
    const float* __restrict__ w,      // (3,768,1,5,5)
    const float* __restrict__ gamma,  // (3,768)
    const float* __restrict__ beta,
    const float* __restrict__ mean,
    const float* __restrict__ var,
    const float* __restrict__ adjg,   // (32768,256)
    float* __restrict__ qw, float* __restrict__ kw, float* __restrict__ vw,
    int* __restrict__ idxout)         // (32768,8)
{
    __shared__ float wLds[25][256];

    if (blockIdx.x >= CONV_BLOCKS) {
        // ---------------- top-8 part: 2 rows per wave ----------------
        int wave = threadIdx.x >> 6;
        int lane = threadIdx.x & 63;
        int row0 = ((blockIdx.x - CONV_BLOCKS) * 4 + wave) * 2;  // 0..32766

        const float* ar0 = adjg + (size_t)row0 * P2;
        const float* ar1 = ar0 + P2;
        float4 a0 = *(const float4*)(ar0 + lane * 4);
        float4 a1 = *(const float4*)(ar1 + lane * 4);
        float v0[4] = {a0.x, a0.y, a0.z, a0.w};
        float v1[4] = {a1.x, a1.y, a1.z, a1.w};

        int myidx0 = 0, myidx1 = 0;
        #pragma unroll
        for (int it = 0; it < KSEL; it++) {
            float b0 = v0[0]; int s0 = 0;
            float b1 = v1[0]; int s1 = 0;
            if (v0[1] > b0) { b0 = v0[1]; s0 = 1; }
            if (v1[1] > b1) { b1 = v1[1]; s1 = 1; }
            if (v0[2] > b0) { b0 = v0[2]; s0 = 2; }
            if (v1[2] > b1) { b1 = v1[2]; s1 = 2; }
            if (v0[3] > b0) { b0 = v0[3]; s0 = 3; }
            if (v1[3] > b1) { b1 = v1[3]; s1 = 3; }
            float g0 = b0, g1 = b1;
            #pragma unroll
            for (int m = 32; m >= 1; m >>= 1) {
                g0 = fmaxf(g0, __shfl_xor(g0, m, 64));
                g1 = fmaxf(g1, __shfl_xor(g1, m, 64));
            }
            unsigned long long m0 = __ballot(b0 == g0);
            unsigned long long m1 = __ballot(b1 == g1);
            int wl0 = (int)__builtin_ctzll(m0);
            int wl1 = (int)__builtin_ctzll(m1);
            int ws0 = __shfl(s0, wl0, 64);
            int ws1 = __shfl(s1, wl1, 64);
            if (lane == it) { myidx0 = wl0 * 4 + ws0; myidx1 = wl1 * 4 + ws1; }
            if (lane == wl0) v0[ws0] = -INFINITY;
            if (lane == wl1) v1[ws1] = -INFINITY;
        }
        if (lane < KSEL) {
            idxout[(size_t)row0 * KSEL + lane]       = myidx0;
            idxout[(size_t)(row0 + 1) * KSEL + lane] = myidx1;
        }
        return;
    }

    // ---------------- conv+BN part (one of q/k/v), TY=4 rows ----------------
    int bi    = blockIdx.x;              // 0..1151
    int which = bi / 384;                // 0=q 1=k 2=v
    int rem   = bi % 384;
    int b     = rem / 48;
    int rem2  = rem % 48;
    int ys    = rem2 / 6;                // 0..7
    int sub   = rem2 % 6;
    int chunk = sub >> 1;
    int xc    = sub & 1;
    int x0    = xc * 16;
    int y0    = ys * 4;                  // 0,4,...,28 (never crosses 16-bdy)
    int c     = chunk * 256 + threadIdx.x;

    int g = which * D + c;
    float inv = gamma[g] * rsqrtf(var[g] + 1e-5f);
    float sh  = beta[g] - mean[g] * inv;
    if (which == 0) {
        const float scale = 0.03608439182435161f;   // 768^-0.5 folded into q
        inv *= scale; sh *= scale;
    }

    // stage BN-folded weights in LDS: [tap][channel] -> lane-stride-1 reads
    {
        const float* wp = w + ((size_t)which * D + c) * 25;
        #pragma unroll
        for (int i = 0; i < 25; i++) wLds[i][threadIdx.x] = wp[i] * inv;
    }
    __syncthreads();

    float* dst = (which == 0) ? qw : (which == 1) ? kw : vw;

    const float* xb = x + (size_t)b * 1024 * D + c;

    // 8-row sliding window (rows y0-2 .. y0+5), 5 columns wide
    float a[8][5];
    bool yok[8];                         // wave-uniform predicates
    #pragma unroll
    for (int i = 0; i < 8; i++) {
        int yy = y0 - 2 + i;
        yok[i] = (yy >= 0 && yy < 32);
        #pragma unroll
        for (int j = 0; j < 5; j++) {
            int xxc = x0 - 2 + j;
            a[i][j] = (yok[i] && xxc >= 0 && xxc < 32)
                      ? xb[(yy * 32 + xxc) * D] : 0.f;
        }
    }

    int head = c / DH, cc = c % DH;
    int n = b * HEADS + head;
    int A = y0 >> 4;                     // same for all 4 rows of the strip

    #pragma unroll                       // FULL unroll: shifts become renames
    for (int t = 0; t < 16; t++) {
        int xx = x0 + t;
        float s[4] = {0.f, 0.f, 0.f, 0.f};
        #pragma unroll
        for (int i = 0; i < 5; i++)
        #pragma unroll
        for (int j = 0; j < 5; j++) {
            float wv = wLds[i * 5 + j][threadIdx.x];
            s[0] = fmaf(a[0 + i][j], wv, s[0]);
            s[1] = fmaf(a[1 + i][j], wv, s[1]);
            s[2] = fmaf(a[2 + i][j], wv, s[2]);
            s[3] = fmaf(a[3 + i][j], wv, s[3]);
        }
        int j0 = xx & 15, Bq = xx >> 4;
        int slot = A * 2 + Bq;
        #pragma unroll
        for (int r = 0; r < 4; r++) {
            int yq = y0 + r;
            int i0 = yq & 15;
            int win = i0 * 16 + j0;
            size_t off = (((size_t)n * P2 + win) * 4 + slot) * DH + cc;
            dst[off] = s[r] + sh;
        }
        if (t < 15) {                    // no dead refill on the last step
            #pragma unroll
            for (int i = 0; i < 8; i++)
            #pragma unroll
            for (int j = 0; j < 4; j++)
                a[i][j] = a[i][j + 1];
            int xn = xx + 3;
            bool xok = (xn < 32);
            #pragma unroll
            for (int i = 0; i < 8; i++) {
                int yy = y0 - 2 + i;
                a[i][4] = (yok[i] && xok) ? xb[(yy * 32 + xn) * D] : 0.f;
            }
        }
    }
}

// ---------------------------------------------------------------------------
// Kernel 2: attention — BARRIER-FREE (round 9). r8 isolated attn at 46.4us
// with VALUBusy 39% / HBM 17% / Occupancy 35%: latency-bound. All LDS here
// is wave-private, but __syncthreads() coupled the 4 waves: each wave
// stalled until the slowest co-wave's dependent K/V gather finished, and
// the barrier's full-drain killed cross-phase overlap. Replaced with
// wave-local lgkmcnt fences.
// ---------------------------------------------------------------------------
__global__ __launch_bounds__(256) void attn_kernel(
    const int*   __restrict__ idxin,  // (32768, 8)
    const float* __restrict__ qw,     // pre-scaled
    const float* __restrict__ kw,
    const float* __restrict__ vw,
    float* __restrict__ out)          // (8,1024,768) fp32
{
    __shared__ float4 vL[4][32 * 13];
    __shared__ float4 qL[4][4 * 13];
    __shared__ float  pL[4][4 * 36];

    int wave = threadIdx.x >> 6;
    int lane = threadIdx.x & 63;
    int B    = blockIdx.x;                 // 8192 blocks
    int n    = (B & 7) * 16 + (B >> 9);    // 0..127 (XCD swizzle)
    int wing = (B >> 3) & 63;
    int win  = wing * 4 + wave;            // 0..255
    int row  = n * P2 + win;
    int b    = n >> 4, head = n & 15;

    float4* vs4 = vL[wave];
    float4* qs4 = qL[wave];
    float*  ps  = pL[wave];

    int l2 = lane & 31, half = lane >> 5;
    int kk = l2 >> 2, tt = l2 & 3;
    int mywin = idxin[row * KSEL + kk];

    const float4* qp = (const float4*)(qw + ((size_t)n * P2 + win) * 192);
    if (lane < 48) {
        int r = lane / 12, c4 = lane % 12;
        qs4[r * 13 + c4] = qp[lane];
    }

    size_t gbase = (((size_t)n * P2 + mywin) * 4 + tt) * DH + half * 24;
    const float4* srcK = (const float4*)(kw + gbase);
    const float4* srcV = (const float4*)(vw + gbase);
    float4 kregh[6];
    #pragma unroll
    for (int j = 0; j < 6; j++) kregh[j] = srcK[j];
    #pragma unroll
    for (int j = 0; j < 6; j++) vs4[l2 * 13 + half * 6 + j] = srcV[j];
    WAVE_FENCE();                          // was __syncthreads()

    float s4[4];
    #pragma unroll
    for (int r = 0; r < 4; r++) {
        float acc = 0.f;
        #pragma unroll
        for (int j = 0; j < 6; j++) {
            float4 q4 = qs4[r * 13 + half * 6 + j];
            acc = fmaf(q4.x, kregh[j].x, acc);
            acc = fmaf(q4.y, kregh[j].y, acc);
            acc = fmaf(q4.z, kregh[j].z, acc);
            acc = fmaf(q4.w, kregh[j].w, acc);
        }
        s4[r] = acc;
    }
    #pragma unroll
    for (int r = 0; r < 4; r++)
        s4[r] += __shfl_xor(s4[r], 32, 64);

    #pragma unroll
    for (int e = 0; e < 2; e++) {
        int r = 2 * half + e;
        float sv = s4[r];
        float m = sv;
        #pragma unroll
        for (int mm = 16; mm >= 1; mm >>= 1)
            m = fmaxf(m, __shfl_xor(m, mm, 64));
        float p = __expf(sv - m);
        float sum = p;
        #pragma unroll
        for (int mm = 16; mm >= 1; mm >>= 1)
            sum += __shfl_xor(sum, mm, 64);
        ps[r * 36 + l2] = p / sum;
    }
    WAVE_FENCE();                          // was __syncthreads()

    if (lane < 48) {
        int r = lane / 12, c4 = lane % 12;
        const float4* psv = (const float4*)(ps + r * 36);
        float4 acc = {0.f, 0.f, 0.f, 0.f};
        #pragma unroll
        for (int k2q = 0; k2q < 8; k2q++) {
            float4 p4 = psv[k2q];
            float4 v0 = vs4[(k2q * 4 + 0) * 13 + c4];
            float4 v1 = vs4[(k2q * 4 + 1) * 13 + c4];
            float4 v2 = vs4[(k2q * 4 + 2) * 13 + c4];
            float4 v3 = vs4[(k2q * 4 + 3) * 13 + c4];
            acc.x = fmaf(p4.x, v0.x, acc.x); acc.y = fmaf(p4.x, v0.y, acc.y);
            acc.z = fmaf(p4.x, v0.z, acc.z); acc.w = fmaf(p4.x, v0.w, acc.w);
            acc.x = fmaf(p4.y, v1.x, acc.x); acc.y = fmaf(p4.y, v1.y, acc.y);
            acc.z = fmaf(p4.y, v1.z, acc.z); acc.w = fmaf(p4.y, v1.w, acc.w);
            acc.x = fmaf(p4.z, v2.x, acc.x); acc.y = fmaf(p4.z, v2.y, acc.y);
            acc.z = fmaf(p4.z, v2.z, acc.z); acc.w = fmaf(p4.z, v2.w, acc.w);
            acc.x = fmaf(p4.w, v3.x, acc.x); acc.y = fmaf(p4.w, v3.y, acc.y);
            acc.z = fmaf(p4.w, v3.z, acc.z); acc.w = fmaf(p4.w, v3.w, acc.w);
        }
        int i0 = win >> 4, j0 = win & 15;
        int Aq = r >> 1, Bq = r & 1;
        int rowp = Bq * 16 + i0, colp = Aq * 16 + j0;
        float* op = out + ((size_t)b * 1024 + rowp * 32 + colp) * D
                        + head * DH + c4 * 4;
        *(float4*)op = acc;
    }
}

// ---------------------------------------------------------------------------
// Fallback (zero workspace): fully fused, round-3 version.
// ---------------------------------------------------------------------------
__global__ __launch_bounds__(256) void fused_attn(
    const float* __restrict__ x,
    const float* __restrict__ adjg,
    const float* __restrict__ w,
    const float* __restrict__ gamma,
    const float* __restrict__ beta,
    const float* __restrict__ mean,
    const float* __restrict__ var,
    float* __restrict__ out)
{
    __shared__ float wL[3][25][48];
    __shared__ float bnI[3][48], bnS[3][48];
    __shared__ float qL[4][192];
    __shared__ float vL[4][32 * VSTRIDE];
    __shared__ float pL[4][4 * PSTRIDE];

    int tid  = threadIdx.x;
    int wave = tid >> 6, lane = tid & 63;
    int unit = blockIdx.x * 4 + wave;
    int n    = unit >> 8;
    int win  = unit & 255;
    int b    = n >> 4, head = n & 15;

    for (int j = tid; j < 3600; j += 256) {
        int chunk = j / 1200, rem = j % 1200, t = rem / 48, cc = rem % 48;
        wL[chunk][t][cc] = w[(size_t)chunk * D * 25 + (head * DH + cc) * 25 + t];
    }
    for (int j = tid; j < 144; j += 256) {
        int chunk = j / 48, cc = j % 48;
        int g = chunk * D + head * DH + cc;
        float inv = gamma[g] * rsqrtf(var[g] + 1e-5f);
        bnI[chunk][cc] = inv;
        bnS[chunk][cc] = beta[g] - mean[g] * inv;
    }
    __syncthreads();

    float* qs = qL[wave];
    float* vs = vL[wave];
    float* ps = pL[wave];

    const float* arow = adjg + ((size_t)n * P2 + win) * P2;
    float4 av4 = *(const float4*)(arow + lane * 4);
    float vals[4] = {av4.x, av4.y, av4.z, av4.w};

    int l2 = lane & 31;
    int kk = l2 >> 2, tt = l2 & 3;
    int mywin = 0;
    #pragma unroll
    for (int it = 0; it < KSEL; it++) {
        float bv = vals[0]; int bidx = lane * 4;
        #pragma unroll
        for (int s = 1; s < 4; s++)
            if (vals[s] > bv) { bv = vals[s]; bidx = lane * 4 + s; }
        #pragma unroll
        for (int m = 32; m >= 1; m >>= 1) {
            float ov = __shfl_xor(bv, m, 64);
            int   oi = __shfl_xor(bidx, m, 64);
            if (ov > bv || (ov == bv && oi < bidx)) { bv = ov; bidx = oi; }
        }
        if (kk == it) mywin = bidx;
        #pragma unroll
        for (int s = 0; s < 4; s++)
            if (lane * 4 + s == bidx) vals[s] = -INFINITY;
    }

    const float scale = 0.03608439182435161f;
    int i0 = win >> 4, j0 = win & 15;
    const float* xbh = x + (size_t)b * 1024 * D + head * DH;

    #pragma unroll
    for (int e = 0; e < 3; e++) {
        int idx = lane + 64 * e;
        int r = idx / 48, cc = idx % 48;
        int yq  = (r >> 1) * 16 + i0;
        int xq0 = (r & 1) * 16 + j0;
        float acc = 0.f;
        for (int ty = 0; ty < 5; ty++) {
            int yy = yq + ty - 2;
            if (yy < 0 || yy > 31) continue;
            for (int tx = 0; tx < 5; tx++) {
                int xx = xq0 + tx - 2;
                if (xx < 0 || xx > 31) continue;
                acc = fmaf(xbh[(size_t)(yy * 32 + xx) * D + cc],
                           wL[0][ty * 5 + tx][cc], acc);
            }
        }
        qs[idx] = (acc * bnI[0][cc] + bnS[0][cc]) * scale;
    }

    int half  = lane >> 5;
    int chunk = 1 + half;
    float accv[48];
    {
        int yk  = (tt >> 1) * 16 + (mywin >> 4);
        int xk0 = (tt & 1) * 16 + (mywin & 15);
        #pragma unroll
        for (int cc = 0; cc < 48; cc++) accv[cc] = 0.f;
        for (int ty = 0; ty < 5; ty++) {
            int yy = yk + ty - 2;
            if (yy < 0 || yy > 31) continue;
            for (int tx = 0; tx < 5; tx++) {
                int xx = xk0 + tx - 2;
                if (xx < 0 || xx > 31) continue;
                const float* px = xbh + (size_t)(yy * 32 + xx) * D;
                const float* wt = wL[chunk][ty * 5 + tx];
                #pragma unroll
                for (int c4 = 0; c4 < 12; c4++) {
                    float4 xv = *(const float4*)(px + c4 * 4);
                    accv[c4*4+0] = fmaf(xv.x, wt[c4*4+0], accv[c4*4+0]);
                    accv[c4*4+1] = fmaf(xv.y, wt[c4*4+1], accv[c4*4+1]);
                    accv[c4*4+2] = fmaf(xv.z, wt[c4*4+2], accv[c4*4+2]);
                    accv[c4*4+3] = fmaf(xv.w, wt[c4*4+3], accv[c4*4+3]);
                }
            }
        }
        #pragma unroll
        for (int cc = 0; cc < 48; cc++) {
            float val = accv[cc] * bnI[chunk][cc] + bnS[chunk][cc];
            if (half) vs[l2 * VSTRIDE + cc] = val;
            else      accv[cc] = val;
        }
    }
    __syncthreads();

    if (!half) {
        float s4[4] = {0.f, 0.f, 0.f, 0.f};
        #pragma unroll
        for (int c = 0; c < 48; c++) {
            float kc = accv[c];
            s4[0] = fmaf(qs[c],       kc, s4[0]);
            s4[1] = fmaf(qs[48 + c],  kc, s4[1]);
            s4[2] = fmaf(qs[96 + c],  kc, s4[2]);
            s4[3] = fmaf(qs[144 + c], kc, s4[3]);
        }
        #pragma unroll
        for (int r = 0; r < 4; r++) {
            float m = s4[r];
            #pragma unroll
            for (int mm = 16; mm >= 1; mm >>= 1)
                m = fmaxf(m, __shfl_xor(m, mm, 64));
            float p = __expf(s4[r] - m);
            float sum = p;
            #pragma unroll
            for (int mm = 16; mm >= 1; mm >>= 1)
                sum += __shfl_xor(sum, mm, 64);
            ps[r * PSTRIDE + l2] = p / sum;
        }
    }
    __syncthreads();

    #pragma unroll
    for (int e = 0; e < 3; e++) {
        int idx = lane + 64 * e;
        int r = idx / 48, c = idx % 48;
        float acc = 0.f;
        #pragma unroll
        for (int k2 = 0; k2 < 32; k2++)
            acc = fmaf(ps[r * PSTRIDE + k2], vs[k2 * VSTRIDE + c], acc);
        int Aq = r >> 1, Bq = r & 1;
        int rowp = Bq * 16 + i0, colp = Aq * 16 + j0;
        out[((size_t)b * 1024 + rowp * 32 + colp) * D + head * DH + c] = acc;
    }
}

extern "C" void kernel_launch(void* const* d_in, const int* in_sizes, int n_in,
                              void* d_out, int out_size, void* d_ws, size_t ws_size,
                              hipStream_t stream)
{
    const float* x     = (const float*)d_in[0];
    // d_in[1] = noise (unused by reference)
    const float* adjg  = (const float*)d_in[2];
    const float* w     = (const float*)d_in[3];
    const float* gamma = (const float*)d_in[4];
    const float* beta  = (const float*)d_in[5];
    const float* mean  = (const float*)d_in[6];
    const float* var   = (const float*)d_in[7];
    // d_in[8] = sparsity (=8, compile-time KSEL)

    const size_t NQKV   = (size_t)8 * HEADS * P2 * 4 * DH;   // 6291456 elements
    const size_t NROWS  = (size_t)8 * HEADS * P2;            // 32768
    const size_t need3  = 3 * NQKV * sizeof(float) + NROWS * KSEL * sizeof(int);

    if (ws_size >= need3) {
        float* qw  = (float*)d_ws;
        float* kw  = qw + NQKV;
        float* vw  = kw + NQKV;
        int*   idx = (int*)(vw + NQKV);
        prep_kernel<<<CONV_BLOCKS + TOPK_BLOCKS, 256, 0, stream>>>(
            x, w, gamma, beta, mean, var, adjg, qw, kw, vw, idx);
        attn_kernel<<<8192, 256, 0, stream>>>(idx, qw, kw, vw, (float*)d_out);
    } else {
        fused_attn<<<8192, 256, 0, stream>>>(x, adjg, w, gamma, beta, mean, var,
                                             (float*)d_out);
    }
}